// Round 1
// baseline (1417.076 us; speedup 1.0000x reference)
//
#include <hip/hip_runtime.h>
#include <hip/hip_bf16.h>

// Problem constants (from reference)
#define IN_PER_SIDE   40960
#define IN_TOTAL      81920     // 2 * 40960
#define L1            512
#define L2            32
#define L3_           32
#define BATCH         4096

// ---------------------------------------------------------------------------
// Kernel 1: LDS-tiled transpose W_in [512, 81920] -> W_T [81920, 512]
// Both read and write coalesced (32-float contiguous segments per half-wave).
// ---------------------------------------------------------------------------
__global__ __launch_bounds__(256) void transpose_win(
    const float* __restrict__ W, float* __restrict__ WT)
{
    __shared__ float tile[32][33];            // +1 pad: no bank conflicts
    const int jt = blockIdx.x * 32;           // input-feature tile base
    const int ot = blockIdx.y * 32;           // output-neuron tile base
    const int tx = threadIdx.x;               // 0..31
    const int ty = threadIdx.y;               // 0..7

#pragma unroll
    for (int k = 0; k < 4; ++k) {
        int o = ot + ty + 8 * k;
        tile[ty + 8 * k][tx] = W[(size_t)o * IN_TOTAL + jt + tx];
    }
    __syncthreads();
#pragma unroll
    for (int k = 0; k < 4; ++k) {
        int j = jt + ty + 8 * k;
        WT[(size_t)j * L1 + ot + tx] = tile[tx][ty + 8 * k];
    }
}

// ---------------------------------------------------------------------------
// Kernel 2: fully fused NNUE forward, one block per batch row, 512 threads.
//   Phase 1: float4 scan of w/b feature rows -> LDS index list (LDS atomics)
//   Phase 2: thread t = output neuron t; accumulate W_T columns (coalesced)
//   Phase 3-5: tiny dense layers in LDS
// ---------------------------------------------------------------------------
__global__ __launch_bounds__(512) void nnue_fused(
    const float* __restrict__ wf, const float* __restrict__ bfeat,
    const float* __restrict__ WT, const float* __restrict__ W_in, int use_wt,
    const float* __restrict__ b_in,
    const float* __restrict__ W1, const float* __restrict__ b1,
    const float* __restrict__ W2, const float* __restrict__ b2,
    const float* __restrict__ W3, const float* __restrict__ b3,
    float* __restrict__ out)
{
    const int b = blockIdx.x;
    const int t = threadIdx.x;

    __shared__ int   idxs[128];   // max ~60 active features per row
    __shared__ int   cnt;
    __shared__ float l1s[L1];
    __shared__ float l2acc[L2];
    __shared__ float l2s[L2];
    __shared__ float l3s[L3_];

    if (t == 0) cnt = 0;
    if (t < L2) l2acc[t] = 0.0f;
    __syncthreads();

    // ---- Phase 1: scan both perspective rows for nonzeros (values are 1.0)
    const float4* wrow = (const float4*)(wf    + (size_t)b * IN_PER_SIDE);
    const float4* brow = (const float4*)(bfeat + (size_t)b * IN_PER_SIDE);
    const int nvec = IN_PER_SIDE / 4;  // 10240 float4 per side

    for (int i = t; i < nvec; i += 512) {
        float4 v = wrow[i];
        if (v.x != 0.0f) idxs[atomicAdd(&cnt, 1)] = 4 * i + 0;
        if (v.y != 0.0f) idxs[atomicAdd(&cnt, 1)] = 4 * i + 1;
        if (v.z != 0.0f) idxs[atomicAdd(&cnt, 1)] = 4 * i + 2;
        if (v.w != 0.0f) idxs[atomicAdd(&cnt, 1)] = 4 * i + 3;
        float4 u = brow[i];
        if (u.x != 0.0f) idxs[atomicAdd(&cnt, 1)] = IN_PER_SIDE + 4 * i + 0;
        if (u.y != 0.0f) idxs[atomicAdd(&cnt, 1)] = IN_PER_SIDE + 4 * i + 1;
        if (u.z != 0.0f) idxs[atomicAdd(&cnt, 1)] = IN_PER_SIDE + 4 * i + 2;
        if (u.w != 0.0f) idxs[atomicAdd(&cnt, 1)] = IN_PER_SIDE + 4 * i + 3;
    }
    __syncthreads();

    // ---- Phase 2: accumulate active W_in columns; thread t = neuron t
    const int n = cnt;
    float a0 = 0.0f, a1 = 0.0f, a2 = 0.0f, a3 = 0.0f;
    int i = 0;
    if (use_wt) {
        for (; i + 4 <= n; i += 4) {
            a0 += WT[(size_t)idxs[i + 0] * L1 + t];
            a1 += WT[(size_t)idxs[i + 1] * L1 + t];
            a2 += WT[(size_t)idxs[i + 2] * L1 + t];
            a3 += WT[(size_t)idxs[i + 3] * L1 + t];
        }
        for (; i < n; ++i) a0 += WT[(size_t)idxs[i] * L1 + t];
    } else {
        // fallback: strided column reads straight from W_in (slow, correct)
        const float* wr = W_in + (size_t)t * IN_TOTAL;
        for (; i < n; ++i) a0 += wr[idxs[i]];
    }
    float acc = b_in[t] + ((a0 + a1) + (a2 + a3));
    l1s[t] = fminf(fmaxf(acc, 0.0f), 1.0f);
    __syncthreads();

    // ---- Phase 3: l2 = clip(l1 @ W1.T + b1), 32 outputs x 512 inputs
    {
        const int k = t >> 4;          // 16 threads per output k
        const int g = t & 15;
        const float* w = W1 + (size_t)k * L1;
        float p = 0.0f;
        for (int o = g; o < L1; o += 16) p += w[o] * l1s[o];
        atomicAdd(&l2acc[k], p);
    }
    __syncthreads();
    if (t < L2) l2s[t] = fminf(fmaxf(l2acc[t] + b1[t], 0.0f), 1.0f);
    __syncthreads();

    // ---- Phase 4: l3 = clip(l2 @ W2.T + b2), 32x32
    if (t < L3_) {
        const float* w = W2 + (size_t)t * L2;
        float p = b2[t];
#pragma unroll
        for (int q = 0; q < L2; ++q) p += w[q] * l2s[q];
        l3s[t] = fminf(fmaxf(p, 0.0f), 1.0f);
    }
    __syncthreads();

    // ---- Phase 5: out = l3 @ W3.T + b3  (scalar)
    if (t == 0) {
        float p = b3[0];
#pragma unroll
        for (int q = 0; q < L3_; ++q) p += W3[q] * l3s[q];
        out[b] = p;
    }
}

extern "C" void kernel_launch(void* const* d_in, const int* in_sizes, int n_in,
                              void* d_out, int out_size, void* d_ws, size_t ws_size,
                              hipStream_t stream) {
    const float* wf   = (const float*)d_in[0];
    const float* bfeat= (const float*)d_in[1];
    const float* W_in = (const float*)d_in[2];
    const float* b_in = (const float*)d_in[3];
    const float* W1   = (const float*)d_in[4];
    const float* b1   = (const float*)d_in[5];
    const float* W2   = (const float*)d_in[6];
    const float* b2   = (const float*)d_in[7];
    const float* W3   = (const float*)d_in[8];
    const float* b3   = (const float*)d_in[9];
    float* out = (float*)d_out;

    const size_t wt_bytes = (size_t)IN_TOTAL * L1 * sizeof(float); // 167.8 MB
    const int use_wt = (ws_size >= wt_bytes) ? 1 : 0;
    float* WT = (float*)d_ws;

    if (use_wt) {
        dim3 grid(IN_TOTAL / 32, L1 / 32);   // (2560, 16)
        dim3 block(32, 8);
        transpose_win<<<grid, block, 0, stream>>>(W_in, WT);
    }

    nnue_fused<<<BATCH, 512, 0, stream>>>(
        wf, bfeat, WT, W_in, use_wt, b_in, W1, b1, W2, b2, W3, b3, out);
}

// Round 3
// 1411.854 us; speedup vs baseline: 1.0037x; 1.0037x over previous
//
#include <hip/hip_runtime.h>
#include <hip/hip_bf16.h>

// Problem constants (from reference)
#define IN_PER_SIDE   40960
#define IN_TOTAL      81920     // 2 * 40960
#define L1            512
#define L2            32
#define L3_           32
#define BATCH         4096

// clang-native 4-float vector: required by __builtin_nontemporal_load
// (HIP's float4 is a class and is rejected by the builtin).
typedef float v4f __attribute__((ext_vector_type(4)));

// ---------------------------------------------------------------------------
// Kernel 1: LDS-tiled transpose W_in [512, 81920] -> W_T [81920, 512]
// 64x64 tiles, float4 on both global sides. LDS pad 65 (==1 mod 32) keeps
// all LDS access <=2-way bank aliasing (free on CDNA4).
// W_in is read exactly once per launch -> nontemporal (don't pollute L3;
// we want WT to stay L3-resident for the gather kernel).
// ---------------------------------------------------------------------------
__global__ __launch_bounds__(256) void transpose_win(
    const float* __restrict__ W, float* __restrict__ WT)
{
    __shared__ float tile[64][65];
    const int jt = blockIdx.x * 64;           // input-feature tile base
    const int ot = blockIdx.y * 64;           // output-neuron tile base
    const int tx = threadIdx.x;               // 0..15  (float4 column)
    const int ty = threadIdx.y;               // 0..15  (row)

#pragma unroll
    for (int k = 0; k < 4; ++k) {
        const int o = ty + 16 * k;
        const v4f* p = (const v4f*)&W[(size_t)(ot + o) * IN_TOTAL + jt + 4 * tx];
        v4f v = __builtin_nontemporal_load(p);
        tile[4 * tx + 0][o] = v.x;
        tile[4 * tx + 1][o] = v.y;
        tile[4 * tx + 2][o] = v.z;
        tile[4 * tx + 3][o] = v.w;
    }
    __syncthreads();
#pragma unroll
    for (int k = 0; k < 4; ++k) {
        const int j = ty + 16 * k;
        v4f v;
        v.x = tile[j][4 * tx + 0];
        v.y = tile[j][4 * tx + 1];
        v.z = tile[j][4 * tx + 2];
        v.w = tile[j][4 * tx + 3];
        *(v4f*)&WT[(size_t)(jt + j) * L1 + ot + 4 * tx] = v;
    }
}

// ---------------------------------------------------------------------------
// Kernel 2: fully fused NNUE forward, one block per batch row, 512 threads.
//   Phase 1: nontemporal float4 scan of w/b feature rows -> LDS index list
//   Phase 2: thread t = output neuron t; accumulate W_T columns (coalesced,
//            unroll 8 for memory-level parallelism; mostly L3 hits)
//   Phase 3-5: tiny dense layers, shuffle reductions, no atomics
// ---------------------------------------------------------------------------
__global__ __launch_bounds__(512) void nnue_fused(
    const float* __restrict__ wf, const float* __restrict__ bfeat,
    const float* __restrict__ WT, const float* __restrict__ W_in, int use_wt,
    const float* __restrict__ b_in,
    const float* __restrict__ W1, const float* __restrict__ b1,
    const float* __restrict__ W2, const float* __restrict__ b2,
    const float* __restrict__ W3, const float* __restrict__ b3,
    float* __restrict__ out)
{
    const int b = blockIdx.x;
    const int t = threadIdx.x;

    __shared__ int   idxs[128];   // ~60 active features per row
    __shared__ int   cnt;
    __shared__ float l1s[L1];
    __shared__ float l2acc[L2];
    __shared__ float l2s[L2];
    __shared__ float l3s[L3_];

    if (t == 0) cnt = 0;
    __syncthreads();

    // ---- Phase 1: scan both perspective rows for nonzeros (values are 1.0)
    const v4f* wrow = (const v4f*)(wf    + (size_t)b * IN_PER_SIDE);
    const v4f* brow = (const v4f*)(bfeat + (size_t)b * IN_PER_SIDE);
    const int nvec = IN_PER_SIDE / 4;  // 10240 float4 per side

    for (int i = t; i < nvec; i += 512) {
        v4f v = __builtin_nontemporal_load(wrow + i);
        if (v.x != 0.0f) idxs[atomicAdd(&cnt, 1)] = 4 * i + 0;
        if (v.y != 0.0f) idxs[atomicAdd(&cnt, 1)] = 4 * i + 1;
        if (v.z != 0.0f) idxs[atomicAdd(&cnt, 1)] = 4 * i + 2;
        if (v.w != 0.0f) idxs[atomicAdd(&cnt, 1)] = 4 * i + 3;
        v4f u = __builtin_nontemporal_load(brow + i);
        if (u.x != 0.0f) idxs[atomicAdd(&cnt, 1)] = IN_PER_SIDE + 4 * i + 0;
        if (u.y != 0.0f) idxs[atomicAdd(&cnt, 1)] = IN_PER_SIDE + 4 * i + 1;
        if (u.z != 0.0f) idxs[atomicAdd(&cnt, 1)] = IN_PER_SIDE + 4 * i + 2;
        if (u.w != 0.0f) idxs[atomicAdd(&cnt, 1)] = IN_PER_SIDE + 4 * i + 3;
    }
    __syncthreads();

    // ---- Phase 2: accumulate active W_in columns; thread t = neuron t
    const int n = cnt;
    float a0 = 0.0f, a1 = 0.0f, a2 = 0.0f, a3 = 0.0f;
    int i = 0;
    if (use_wt) {
        for (; i + 8 <= n; i += 8) {
            const float v0 = WT[(size_t)idxs[i + 0] * L1 + t];
            const float v1 = WT[(size_t)idxs[i + 1] * L1 + t];
            const float v2 = WT[(size_t)idxs[i + 2] * L1 + t];
            const float v3 = WT[(size_t)idxs[i + 3] * L1 + t];
            const float v4 = WT[(size_t)idxs[i + 4] * L1 + t];
            const float v5 = WT[(size_t)idxs[i + 5] * L1 + t];
            const float v6 = WT[(size_t)idxs[i + 6] * L1 + t];
            const float v7 = WT[(size_t)idxs[i + 7] * L1 + t];
            a0 += v0; a1 += v1; a2 += v2; a3 += v3;
            a0 += v4; a1 += v5; a2 += v6; a3 += v7;
        }
        for (; i < n; ++i) a0 += WT[(size_t)idxs[i] * L1 + t];
    } else {
        // fallback: strided column reads straight from W_in (slow, correct)
        const float* wr = W_in + (size_t)t * IN_TOTAL;
        for (; i < n; ++i) a0 += wr[idxs[i]];
    }
    float acc = b_in[t] + ((a0 + a1) + (a2 + a3));
    l1s[t] = fminf(fmaxf(acc, 0.0f), 1.0f);
    __syncthreads();

    // ---- Phase 3: l2 = clip(l1 @ W1.T + b1), 32 outputs x 512 inputs.
    // Each output k owned by one group of 16 consecutive lanes (same wave):
    // width-16 shuffle reduce, no atomics.
    {
        const int k = t >> 4;          // 0..31
        const int g = t & 15;
        const float* w = W1 + (size_t)k * L1;
        float p = 0.0f;
        for (int o = g; o < L1; o += 16) p += w[o] * l1s[o];
#pragma unroll
        for (int off = 8; off > 0; off >>= 1) p += __shfl_down(p, off, 16);
        if (g == 0) l2acc[k] = p;
    }
    __syncthreads();
    if (t < L2) l2s[t] = fminf(fmaxf(l2acc[t] + b1[t], 0.0f), 1.0f);
    __syncthreads();

    // ---- Phase 4: l3 = clip(l2 @ W2.T + b2), 32x32
    if (t < L3_) {
        const float* w = W2 + (size_t)t * L2;
        float p = b2[t];
#pragma unroll
        for (int q = 0; q < L2; ++q) p += w[q] * l2s[q];
        l3s[t] = fminf(fmaxf(p, 0.0f), 1.0f);
    }
    __syncthreads();

    // ---- Phase 5: out = l3 @ W3.T + b3  (scalar)
    if (t == 0) {
        float p = b3[0];
#pragma unroll
        for (int q = 0; q < L3_; ++q) p += W3[q] * l3s[q];
        out[b] = p;
    }
}

extern "C" void kernel_launch(void* const* d_in, const int* in_sizes, int n_in,
                              void* d_out, int out_size, void* d_ws, size_t ws_size,
                              hipStream_t stream) {
    const float* wf   = (const float*)d_in[0];
    const float* bfeat= (const float*)d_in[1];
    const float* W_in = (const float*)d_in[2];
    const float* b_in = (const float*)d_in[3];
    const float* W1   = (const float*)d_in[4];
    const float* b1   = (const float*)d_in[5];
    const float* W2   = (const float*)d_in[6];
    const float* b2   = (const float*)d_in[7];
    const float* W3   = (const float*)d_in[8];
    const float* b3   = (const float*)d_in[9];
    float* out = (float*)d_out;

    const size_t wt_bytes = (size_t)IN_TOTAL * L1 * sizeof(float); // 167.8 MB
    const int use_wt = (ws_size >= wt_bytes) ? 1 : 0;
    float* WT = (float*)d_ws;

    if (use_wt) {
        dim3 grid(IN_TOTAL / 64, L1 / 64);   // (1280, 8)
        dim3 block(16, 16);
        transpose_win<<<grid, block, 0, stream>>>(W_in, WT);
    }

    nnue_fused<<<BATCH, 512, 0, stream>>>(
        wf, bfeat, WT, W_in, use_wt, b_in, W1, b1, W2, b2, W3, b3, out);
}